// Round 4
// baseline (144.893 us; speedup 1.0000x reference)
//
#include <hip/hip_runtime.h>
#include <math.h>

#define N_X   20000
#define N_ELL 48
#define N_K   1024
#define N_TAU 600
#define SPLIT 4
#define CHUNK (N_TAU / SPLIT)   // 150

// ---------------------------------------------------------------------------
// bf16 helpers (manual RNE pack/unpack)
__device__ __forceinline__ unsigned int bf16_rne(float f) {
    unsigned int u = __float_as_uint(f);
    return (u + 0x7FFFu + ((u >> 16) & 1u)) >> 16;
}
__device__ __forceinline__ float bf16_lo(unsigned int w) { return __uint_as_float(w << 16); }
__device__ __forceinline__ float bf16_hi(unsigned int w) { return __uint_as_float(w & 0xFFFF0000u); }

// ---------------------------------------------------------------------------
// Repack four [N_X][N_ELL] fp32 tables into [N_X][N_ELL] bf16x4 (uint2).
__global__ __launch_bounds__(256) void repack_kernel(
    const float* __restrict__ p0, const float* __restrict__ p1,
    const float* __restrict__ p2, const float* __restrict__ pe,
    uint2* __restrict__ P)
{
    const int total = N_X * N_ELL;
    for (int idx = blockIdx.x * blockDim.x + threadIdx.x; idx < total;
         idx += gridDim.x * blockDim.x) {
        uint2 v;
        v.x = bf16_rne(p0[idx]) | (bf16_rne(p1[idx]) << 16);
        v.y = bf16_rne(p2[idx]) | (bf16_rne(pe[idx]) << 16);
        P[idx] = v;
    }
}

// ---------------------------------------------------------------------------
// Main kernel: grid = N_K*SPLIT blocks of 256 threads (4 waves).
// Block handles one (k, tau-chunk). lane = ell. Slow (large-k) blocks first.
// Writes partial integrals Tlp/Elp[part][ell][k].
__global__ __launch_bounds__(256) void tl_el_packed(
    const float* __restrict__ k, const float* __restrict__ tau,
    const float* __restrict__ tau0p,
    const float* __restrict__ S0, const float* __restrict__ S1,
    const float* __restrict__ S2, const float* __restrict__ SE,
    const float* __restrict__ bx, const uint2* __restrict__ P,
    float* __restrict__ Tlp, float* __restrict__ Elp)
{
    const int bid  = blockIdx.x;
    const int part = bid & (SPLIT - 1);
    const int kidx = (N_K - 1) - (bid >> 2);     // slow-first: large k dispatched early
    const int t0   = part * CHUNK;
    const int tid  = threadIdx.x;
    const int wave = tid >> 6;
    const int lane = tid & 63;
    const int ell  = (lane < N_ELL) ? lane : (N_ELL - 1);

    __shared__ unsigned int off_s[CHUNK];   // byte offset of row i0
    __shared__ float        w_s[CHUNK];
    __shared__ float4       S4_s[CHUNK];    // wt-folded sources {s0,s1,s2,se}
    __shared__ float        redT[4][N_ELL];
    __shared__ float        redE[4][N_ELL];

    const float kk    = k[kidx];
    const float tau0  = tau0p[0];
    const float xmin  = bx[0];
    const float xmax  = bx[N_X - 1];
    const float scale = (float)(N_X - 1) / (xmax - xmin);

    // per-tau uniform precompute for this chunk (one pass: CHUNK=150 < 256)
    if (tid < CHUNK) {
        int t = t0 + tid;
        float tt = tau[t];
        float tp = (t > 0)         ? tau[t - 1] : tt;
        float tn = (t < N_TAU - 1) ? tau[t + 1] : tt;
        float wt = 0.5f * (tn - tp);
        float x   = kk * (tau0 - tt);
        float pos = (x - xmin) * scale;
        pos = fminf(fmaxf(pos, 0.0f), (float)(N_X - 1));
        int i0 = (int)pos;                      // pos >= 0 -> trunc == floor
        if (i0 > N_X - 2) i0 = N_X - 2;
        off_s[tid] = (unsigned int)i0 * (N_ELL * 8u);
        w_s[tid]   = pos - (float)i0;
        size_t sb = (size_t)kidx * N_TAU + t;
        float4 s;
        s.x = wt * S0[sb];
        s.y = wt * S1[sb];
        s.z = wt * S2[sb];
        s.w = wt * SE[sb];
        S4_s[tid] = s;
    }
    __syncthreads();

    float accT = 0.0f, accE = 0.0f;
    const char* Pbase = (const char*)P;
    const unsigned int ell8 = (unsigned int)ell * 8u;

    #pragma unroll 4
    for (int i = wave; i < CHUNK; i += 4) {
        unsigned int voff = off_s[i] + ell8;
        float  w = w_s[i];
        float4 s = S4_s[i];

        uint2 ra = *(const uint2*)(Pbase + voff);          // row i0
        uint2 rb = *(const uint2*)(Pbase + voff + N_ELL*8); // row i0+1 (imm offset)

        float a0 = bf16_lo(ra.x), a1 = bf16_hi(ra.x);
        float a2 = bf16_lo(ra.y), ae = bf16_hi(ra.y);
        float b0 = bf16_lo(rb.x), b1 = bf16_hi(rb.x);
        float b2 = bf16_lo(rb.y), be = bf16_hi(rb.y);

        float v0 = fmaf(w, b0 - a0, a0);
        float v1 = fmaf(w, b1 - a1, a1);
        float v2 = fmaf(w, b2 - a2, a2);
        float ve = fmaf(w, be - ae, ae);

        float tacc = s.x * v0;
        tacc = fmaf(s.y, v1, tacc);
        tacc = fmaf(s.z, v2, tacc);
        accT += tacc;
        accE = fmaf(s.w, ve, accE);
    }

    if (lane < N_ELL) { redT[wave][lane] = accT; redE[wave][lane] = accE; }
    __syncthreads();
    if (tid < N_ELL) {
        float sT = (redT[0][tid] + redT[1][tid]) + (redT[2][tid] + redT[3][tid]);
        float sE = (redE[0][tid] + redE[1][tid]) + (redE[2][tid] + redE[3][tid]);
        Tlp[((size_t)part * N_ELL + tid) * N_K + kidx] = sT;
        Elp[((size_t)part * N_ELL + tid) * N_K + kidx] = sE;
    }
}

// ---------------------------------------------------------------------------
// Fallback (round-1, fp32 path) if ws can't hold the packed table + partials.
__global__ __launch_bounds__(256) void tl_el_kernel(
    const float* __restrict__ k, const float* __restrict__ tau,
    const float* __restrict__ tau0p,
    const float* __restrict__ S0, const float* __restrict__ S1,
    const float* __restrict__ S2, const float* __restrict__ SE,
    const float* __restrict__ bx,
    const float* __restrict__ p0, const float* __restrict__ p1,
    const float* __restrict__ p2, const float* __restrict__ pe,
    float* __restrict__ Tl, float* __restrict__ El)
{
    const int kidx = blockIdx.x;
    const int tid  = threadIdx.x;
    const int wave = tid >> 6;
    const int lane = tid & 63;
    const int ell  = (lane < N_ELL) ? lane : (N_ELL - 1);

    const float kk    = k[kidx];
    const float tau0  = tau0p[0];
    const float xmin  = bx[0];
    const float xmax  = bx[N_X - 1];
    const float scale = (float)(N_X - 1) / (xmax - xmin);

    const float* Srow0 = S0 + (size_t)kidx * N_TAU;
    const float* Srow1 = S1 + (size_t)kidx * N_TAU;
    const float* Srow2 = S2 + (size_t)kidx * N_TAU;
    const float* SrowE = SE + (size_t)kidx * N_TAU;

    float accT = 0.0f, accE = 0.0f;

    for (int t = wave; t < N_TAU; t += 4) {
        float tt    = tau[t];
        float tprev = (t > 0)         ? tau[t - 1] : tt;
        float tnext = (t < N_TAU - 1) ? tau[t + 1] : tt;
        float wt    = 0.5f * (tnext - tprev);

        float x   = kk * (tau0 - tt);
        float pos = (x - xmin) * scale;
        pos = fminf(fmaxf(pos, 0.0f), (float)(N_X - 1));
        int i0 = (int)floorf(pos);
        if (i0 > N_X - 2) i0 = N_X - 2;
        float w = pos - (float)i0;

        int base = i0 * N_ELL + ell;
        float y00 = p0[base], y01 = p0[base + N_ELL];
        float y10 = p1[base], y11 = p1[base + N_ELL];
        float y20 = p2[base], y21 = p2[base + N_ELL];
        float ye0 = pe[base], ye1 = pe[base + N_ELL];

        float a0 = fmaf(w, y01 - y00, y00);
        float a1 = fmaf(w, y11 - y10, y10);
        float a2 = fmaf(w, y21 - y20, y20);
        float ae = fmaf(w, ye1 - ye0, ye0);

        float s0 = Srow0[t], s1 = Srow1[t], s2 = Srow2[t], se = SrowE[t];

        float srcT = s0 * a0 + s1 * a1 + s2 * a2;
        accT = fmaf(wt, srcT, accT);
        accE = fmaf(wt, se * ae, accE);
    }

    __shared__ float redT[4][N_ELL];
    __shared__ float redE[4][N_ELL];
    if (lane < N_ELL) { redT[wave][lane] = accT; redE[wave][lane] = accE; }
    __syncthreads();
    if (tid < N_ELL) {
        float sT = (redT[0][tid] + redT[1][tid]) + (redT[2][tid] + redT[3][tid]);
        float sE = (redE[0][tid] + redE[1][tid]) + (redE[2][tid] + redE[3][tid]);
        Tl[tid * N_K + kidx] = sT;
        El[tid * N_K + kidx] = sE;
    }
}

// ---------------------------------------------------------------------------
// Kernel 2: one block per ell; sums nparts partials, trapezoid over k.
__global__ __launch_bounds__(256) void cl_kernel(
    const float* __restrict__ k,
    const float* __restrict__ Asp, const float* __restrict__ nsp,
    const float* __restrict__ Tlp, const float* __restrict__ Elp,
    int nparts, float* __restrict__ out)
{
    const int ell = blockIdx.x;
    const int tid = threadIdx.x;
    const float A_s = Asp[0];
    const float n_s = nsp[0];
    const float two_pi2 = 2.0f * (float)M_PI * (float)M_PI;

    float aTT = 0.0f, aEE = 0.0f, aTE = 0.0f;
    for (int i = tid; i < N_K; i += 256) {
        float kv    = k[i];
        float kprev = (i > 0)       ? k[i - 1] : kv;
        float knext = (i < N_K - 1) ? k[i + 1] : kv;
        float dkw   = 0.5f * (knext - kprev);
        float Pw = A_s * powf(kv / 0.05f, n_s - 1.0f) * two_pi2 / kv;
        float ww = dkw * Pw;
        float tl = 0.0f, el = 0.0f;
        for (int p = 0; p < nparts; ++p) {
            tl += Tlp[((size_t)p * N_ELL + ell) * N_K + i];
            el += Elp[((size_t)p * N_ELL + ell) * N_K + i];
        }
        aTT = fmaf(ww * tl, tl, aTT);
        aEE = fmaf(ww * el, el, aEE);
        aTE = fmaf(ww * tl, el, aTE);
    }

    for (int off = 32; off > 0; off >>= 1) {
        aTT += __shfl_down(aTT, off, 64);
        aEE += __shfl_down(aEE, off, 64);
        aTE += __shfl_down(aTE, off, 64);
    }
    __shared__ float red[3][4];
    const int wave = tid >> 6, lane = tid & 63;
    if (lane == 0) { red[0][wave] = aTT; red[1][wave] = aEE; red[2][wave] = aTE; }
    __syncthreads();
    if (tid == 0) {
        const float c = 2.0f / (float)M_PI;
        out[0 * N_ELL + ell] = c * ((red[0][0] + red[0][1]) + (red[0][2] + red[0][3]));
        out[1 * N_ELL + ell] = c * ((red[1][0] + red[1][1]) + (red[1][2] + red[1][3]));
        out[2 * N_ELL + ell] = c * ((red[2][0] + red[2][1]) + (red[2][2] + red[2][3]));
    }
}

extern "C" void kernel_launch(void* const* d_in, const int* in_sizes, int n_in,
                              void* d_out, int out_size, void* d_ws, size_t ws_size,
                              hipStream_t stream) {
    const float* k    = (const float*)d_in[0];
    const float* tau  = (const float*)d_in[1];
    const float* tau0 = (const float*)d_in[2];
    const float* S0   = (const float*)d_in[3];
    const float* S1   = (const float*)d_in[4];
    const float* S2   = (const float*)d_in[5];
    const float* SE   = (const float*)d_in[6];
    const float* bx   = (const float*)d_in[7];
    const float* p0   = (const float*)d_in[8];
    const float* p1   = (const float*)d_in[9];
    const float* p2   = (const float*)d_in[10];
    const float* pe   = (const float*)d_in[11];
    const float* A_s  = (const float*)d_in[12];
    const float* n_s  = (const float*)d_in[13];
    float* out = (float*)d_out;

    const size_t P_bytes    = (size_t)N_X * N_ELL * sizeof(uint2);              // 7.68 MB
    const size_t part_bytes = (size_t)SPLIT * N_ELL * N_K * sizeof(float);      // 786 KB

    if (ws_size >= P_bytes + 2 * part_bytes) {
        uint2* P   = (uint2*)d_ws;
        float* Tlp = (float*)((char*)d_ws + P_bytes);
        float* Elp = (float*)((char*)d_ws + P_bytes + part_bytes);

        repack_kernel<<<(N_X * N_ELL + 255) / 256, 256, 0, stream>>>(p0, p1, p2, pe, P);
        tl_el_packed<<<N_K * SPLIT, 256, 0, stream>>>(k, tau, tau0, S0, S1, S2, SE, bx,
                                                      P, Tlp, Elp);
        cl_kernel<<<N_ELL, 256, 0, stream>>>(k, A_s, n_s, Tlp, Elp, SPLIT, out);
    } else {
        float* Tl = (float*)d_ws;
        float* El = Tl + (size_t)N_ELL * N_K;
        tl_el_kernel<<<N_K, 256, 0, stream>>>(k, tau, tau0, S0, S1, S2, SE, bx,
                                              p0, p1, p2, pe, Tl, El);
        cl_kernel<<<N_ELL, 256, 0, stream>>>(k, A_s, n_s, Tl, El, 1, out);
    }
}

// Round 5
// 133.843 us; speedup vs baseline: 1.0826x; 1.0826x over previous
//
#include <hip/hip_runtime.h>
#include <math.h>

#define N_X   20000
#define N_ELL 48
#define N_K   1024
#define N_TAU 600
#define SPLIT 4
#define CHUNK (N_TAU / SPLIT)   // 150

// ---------------------------------------------------------------------------
// fp16 helpers
__device__ __forceinline__ unsigned int pack_half2(float lo, float hi) {
    _Float16 l = (_Float16)lo, h = (_Float16)hi;
    unsigned short lu = __builtin_bit_cast(unsigned short, l);
    unsigned short hu = __builtin_bit_cast(unsigned short, h);
    return (unsigned int)lu | ((unsigned int)hu << 16);
}
// v_dot2_f32_f16: d = a.lo*b.lo + a.hi*b.hi + c  (f32 accumulate)
__device__ __forceinline__ float fdot2(unsigned int a, unsigned int b, float c) {
    float d;
    asm("v_dot2_f32_f16 %0, %1, %2, %3" : "=v"(d) : "v"(a), "v"(b), "v"(c));
    return d;
}

// ---------------------------------------------------------------------------
// Repack: P[x][ell] = 16B {h2(p0[x],p0[x+1]), h2(p1..), h2(p2..), h2(pe..)}
// so one dwordx4 per (x,ell) yields both interp rows for all 4 tables.
__global__ __launch_bounds__(256) void repack_kernel(
    const float* __restrict__ p0, const float* __restrict__ p1,
    const float* __restrict__ p2, const float* __restrict__ pe,
    uint4* __restrict__ P)
{
    const int total = N_X * N_ELL;
    for (int idx = blockIdx.x * blockDim.x + threadIdx.x; idx < total;
         idx += gridDim.x * blockDim.x) {
        int x = idx / N_ELL;
        int e = idx - x * N_ELL;
        int xn = (x < N_X - 1) ? x + 1 : x;
        int a = x * N_ELL + e, b = xn * N_ELL + e;
        uint4 v;
        v.x = pack_half2(p0[a], p0[b]);
        v.y = pack_half2(p1[a], p1[b]);
        v.z = pack_half2(p2[a], p2[b]);
        v.w = pack_half2(pe[a], pe[b]);
        P[idx] = v;
    }
}

// ---------------------------------------------------------------------------
// Main kernel: grid = N_K*SPLIT blocks of 256 threads (4 waves), lane = ell.
// Per-tau metadata folded into fp16 pairs (wt*s*(1-w), wt*s*w) in LDS; hot
// loop is 1 dwordx4 gather + 4 v_dot2_f32_f16 per cell.
__global__ __launch_bounds__(256) void tl_el_packed(
    const float* __restrict__ k, const float* __restrict__ tau,
    const float* __restrict__ tau0p,
    const float* __restrict__ S0, const float* __restrict__ S1,
    const float* __restrict__ S2, const float* __restrict__ SE,
    const float* __restrict__ bx, const uint4* __restrict__ P,
    float* __restrict__ Tlp, float* __restrict__ Elp)
{
    const int bid  = blockIdx.x;
    const int part = bid & (SPLIT - 1);
    const int kidx = (N_K - 1) - (bid >> 2);   // slow-first: large k dispatched early
    const int t0   = part * CHUNK;
    const int tid  = threadIdx.x;
    const int wave = tid >> 6;
    const int lane = tid & 63;
    const int ell  = (lane < N_ELL) ? lane : (N_ELL - 1);

    __shared__ unsigned int off_s[CHUNK];   // byte offset of row i0 in P
    __shared__ uint4        W2_s[CHUNK];    // 4x half2 {wt*s*(1-w), wt*s*w}
    __shared__ float        redT[4][N_ELL];
    __shared__ float        redE[4][N_ELL];

    const float kk    = k[kidx];
    const float tau0  = tau0p[0];
    const float xmin  = bx[0];
    const float xmax  = bx[N_X - 1];
    const float scale = (float)(N_X - 1) / (xmax - xmin);

    if (tid < CHUNK) {
        int t = t0 + tid;
        float tt = tau[t];
        float tp = (t > 0)         ? tau[t - 1] : tt;
        float tn = (t < N_TAU - 1) ? tau[t + 1] : tt;
        float wt = 0.5f * (tn - tp);
        float x   = kk * (tau0 - tt);
        float pos = (x - xmin) * scale;
        pos = fminf(fmaxf(pos, 0.0f), (float)(N_X - 1));
        int i0 = (int)pos;                   // pos >= 0 -> trunc == floor
        if (i0 > N_X - 2) i0 = N_X - 2;
        float w  = pos - (float)i0;
        float om = 1.0f - w;
        size_t sb = (size_t)kidx * N_TAU + t;
        float s0 = wt * S0[sb], s1 = wt * S1[sb];
        float s2 = wt * S2[sb], se = wt * SE[sb];
        uint4 w2;
        w2.x = pack_half2(s0 * om, s0 * w);
        w2.y = pack_half2(s1 * om, s1 * w);
        w2.z = pack_half2(s2 * om, s2 * w);
        w2.w = pack_half2(se * om, se * w);
        W2_s[tid]  = w2;
        off_s[tid] = (unsigned int)i0 * (N_ELL * 16u);
    }
    __syncthreads();

    const char* Pb = (const char*)P;
    const unsigned int elloff = (unsigned int)ell * 16u;
    float aT0 = 0.0f, aT1 = 0.0f, aT2 = 0.0f, aE = 0.0f;

    #pragma unroll 4
    for (int i = wave; i < CHUNK; i += 4) {
        unsigned int voff = off_s[i] + elloff;
        uint4 pr = *(const uint4*)(Pb + voff);
        uint4 w2 = W2_s[i];
        aT0 = fdot2(pr.x, w2.x, aT0);
        aT1 = fdot2(pr.y, w2.y, aT1);
        aT2 = fdot2(pr.z, w2.z, aT2);
        aE  = fdot2(pr.w, w2.w, aE);
    }
    float accT = (aT0 + aT1) + aT2;

    if (lane < N_ELL) { redT[wave][lane] = accT; redE[wave][lane] = aE; }
    __syncthreads();
    if (tid < N_ELL) {
        float sT = (redT[0][tid] + redT[1][tid]) + (redT[2][tid] + redT[3][tid]);
        float sE = (redE[0][tid] + redE[1][tid]) + (redE[2][tid] + redE[3][tid]);
        Tlp[((size_t)part * N_ELL + tid) * N_K + kidx] = sT;
        Elp[((size_t)part * N_ELL + tid) * N_K + kidx] = sE;
    }
}

// ---------------------------------------------------------------------------
// Fallback (fp32 path) if ws can't hold the packed table + partials.
__global__ __launch_bounds__(256) void tl_el_kernel(
    const float* __restrict__ k, const float* __restrict__ tau,
    const float* __restrict__ tau0p,
    const float* __restrict__ S0, const float* __restrict__ S1,
    const float* __restrict__ S2, const float* __restrict__ SE,
    const float* __restrict__ bx,
    const float* __restrict__ p0, const float* __restrict__ p1,
    const float* __restrict__ p2, const float* __restrict__ pe,
    float* __restrict__ Tl, float* __restrict__ El)
{
    const int kidx = blockIdx.x;
    const int tid  = threadIdx.x;
    const int wave = tid >> 6;
    const int lane = tid & 63;
    const int ell  = (lane < N_ELL) ? lane : (N_ELL - 1);

    const float kk    = k[kidx];
    const float tau0  = tau0p[0];
    const float xmin  = bx[0];
    const float xmax  = bx[N_X - 1];
    const float scale = (float)(N_X - 1) / (xmax - xmin);

    const float* Srow0 = S0 + (size_t)kidx * N_TAU;
    const float* Srow1 = S1 + (size_t)kidx * N_TAU;
    const float* Srow2 = S2 + (size_t)kidx * N_TAU;
    const float* SrowE = SE + (size_t)kidx * N_TAU;

    float accT = 0.0f, accE = 0.0f;

    for (int t = wave; t < N_TAU; t += 4) {
        float tt    = tau[t];
        float tprev = (t > 0)         ? tau[t - 1] : tt;
        float tnext = (t < N_TAU - 1) ? tau[t + 1] : tt;
        float wt    = 0.5f * (tnext - tprev);

        float x   = kk * (tau0 - tt);
        float pos = (x - xmin) * scale;
        pos = fminf(fmaxf(pos, 0.0f), (float)(N_X - 1));
        int i0 = (int)floorf(pos);
        if (i0 > N_X - 2) i0 = N_X - 2;
        float w = pos - (float)i0;

        int base = i0 * N_ELL + ell;
        float y00 = p0[base], y01 = p0[base + N_ELL];
        float y10 = p1[base], y11 = p1[base + N_ELL];
        float y20 = p2[base], y21 = p2[base + N_ELL];
        float ye0 = pe[base], ye1 = pe[base + N_ELL];

        float a0 = fmaf(w, y01 - y00, y00);
        float a1 = fmaf(w, y11 - y10, y10);
        float a2 = fmaf(w, y21 - y20, y20);
        float ae = fmaf(w, ye1 - ye0, ye0);

        float s0 = Srow0[t], s1 = Srow1[t], s2 = Srow2[t], se = SrowE[t];

        float srcT = s0 * a0 + s1 * a1 + s2 * a2;
        accT = fmaf(wt, srcT, accT);
        accE = fmaf(wt, se * ae, accE);
    }

    __shared__ float redT[4][N_ELL];
    __shared__ float redE[4][N_ELL];
    if (lane < N_ELL) { redT[wave][lane] = accT; redE[wave][lane] = accE; }
    __syncthreads();
    if (tid < N_ELL) {
        float sT = (redT[0][tid] + redT[1][tid]) + (redT[2][tid] + redT[3][tid]);
        float sE = (redE[0][tid] + redE[1][tid]) + (redE[2][tid] + redE[3][tid]);
        Tl[tid * N_K + kidx] = sT;
        El[tid * N_K + kidx] = sE;
    }
}

// ---------------------------------------------------------------------------
// Kernel 2: one block per ell; sums nparts partials, trapezoid over k.
__global__ __launch_bounds__(256) void cl_kernel(
    const float* __restrict__ k,
    const float* __restrict__ Asp, const float* __restrict__ nsp,
    const float* __restrict__ Tlp, const float* __restrict__ Elp,
    int nparts, float* __restrict__ out)
{
    const int ell = blockIdx.x;
    const int tid = threadIdx.x;
    const float A_s = Asp[0];
    const float n_s = nsp[0];
    const float two_pi2 = 2.0f * (float)M_PI * (float)M_PI;

    float aTT = 0.0f, aEE = 0.0f, aTE = 0.0f;
    for (int i = tid; i < N_K; i += 256) {
        float kv    = k[i];
        float kprev = (i > 0)       ? k[i - 1] : kv;
        float knext = (i < N_K - 1) ? k[i + 1] : kv;
        float dkw   = 0.5f * (knext - kprev);
        float Pw = A_s * powf(kv / 0.05f, n_s - 1.0f) * two_pi2 / kv;
        float ww = dkw * Pw;
        float tl = 0.0f, el = 0.0f;
        for (int p = 0; p < nparts; ++p) {
            tl += Tlp[((size_t)p * N_ELL + ell) * N_K + i];
            el += Elp[((size_t)p * N_ELL + ell) * N_K + i];
        }
        aTT = fmaf(ww * tl, tl, aTT);
        aEE = fmaf(ww * el, el, aEE);
        aTE = fmaf(ww * tl, el, aTE);
    }

    for (int off = 32; off > 0; off >>= 1) {
        aTT += __shfl_down(aTT, off, 64);
        aEE += __shfl_down(aEE, off, 64);
        aTE += __shfl_down(aTE, off, 64);
    }
    __shared__ float red[3][4];
    const int wave = tid >> 6, lane = tid & 63;
    if (lane == 0) { red[0][wave] = aTT; red[1][wave] = aEE; red[2][wave] = aTE; }
    __syncthreads();
    if (tid == 0) {
        const float c = 2.0f / (float)M_PI;
        out[0 * N_ELL + ell] = c * ((red[0][0] + red[0][1]) + (red[0][2] + red[0][3]));
        out[1 * N_ELL + ell] = c * ((red[1][0] + red[1][1]) + (red[1][2] + red[1][3]));
        out[2 * N_ELL + ell] = c * ((red[2][0] + red[2][1]) + (red[2][2] + red[2][3]));
    }
}

extern "C" void kernel_launch(void* const* d_in, const int* in_sizes, int n_in,
                              void* d_out, int out_size, void* d_ws, size_t ws_size,
                              hipStream_t stream) {
    const float* k    = (const float*)d_in[0];
    const float* tau  = (const float*)d_in[1];
    const float* tau0 = (const float*)d_in[2];
    const float* S0   = (const float*)d_in[3];
    const float* S1   = (const float*)d_in[4];
    const float* S2   = (const float*)d_in[5];
    const float* SE   = (const float*)d_in[6];
    const float* bx   = (const float*)d_in[7];
    const float* p0   = (const float*)d_in[8];
    const float* p1   = (const float*)d_in[9];
    const float* p2   = (const float*)d_in[10];
    const float* pe   = (const float*)d_in[11];
    const float* A_s  = (const float*)d_in[12];
    const float* n_s  = (const float*)d_in[13];
    float* out = (float*)d_out;

    const size_t P_bytes    = (size_t)N_X * N_ELL * sizeof(uint4);              // 15.36 MB
    const size_t part_bytes = (size_t)SPLIT * N_ELL * N_K * sizeof(float);      // 786 KB

    if (ws_size >= P_bytes + 2 * part_bytes) {
        uint4* P   = (uint4*)d_ws;
        float* Tlp = (float*)((char*)d_ws + P_bytes);
        float* Elp = (float*)((char*)d_ws + P_bytes + part_bytes);

        repack_kernel<<<(N_X * N_ELL + 255) / 256, 256, 0, stream>>>(p0, p1, p2, pe, P);
        tl_el_packed<<<N_K * SPLIT, 256, 0, stream>>>(k, tau, tau0, S0, S1, S2, SE, bx,
                                                      P, Tlp, Elp);
        cl_kernel<<<N_ELL, 256, 0, stream>>>(k, A_s, n_s, Tlp, Elp, SPLIT, out);
    } else {
        float* Tl = (float*)d_ws;
        float* El = Tl + (size_t)N_ELL * N_K;
        tl_el_kernel<<<N_K, 256, 0, stream>>>(k, tau, tau0, S0, S1, S2, SE, bx,
                                              p0, p1, p2, pe, Tl, El);
        cl_kernel<<<N_ELL, 256, 0, stream>>>(k, A_s, n_s, Tl, El, 1, out);
    }
}